// Round 8
// baseline (162.934 us; speedup 1.0000x reference)
//
#include <hip/hip_runtime.h>
#include <math.h>

// Problem constants (fixed by setup_inputs): B=4096, T=512, Q=4
#define T_DIM 512
#define GAMMA_F 0.997f
#define EPS_F 1e-3f
// log2(0.997)
#define LOG2_GAMMA (-0.0043345907f)
#define WIDTH 60            // outputs per wave-task (lanes 60..63 are halo)
#define TASKS_PER_ROW 9     // ceil(512/60): 8x60 + 1x32
#define NBLOCKS 1024
#define TPB 256

typedef float v4f __attribute__((ext_vector_type(4)));

__device__ __forceinline__ float inv_rescale_f(float x) {
    float s = (x > 0.f) ? 1.f : ((x < 0.f) ? -1.f : 0.f);
    float sqrt_arg = 1.f + 4.f * EPS_F * (fabsf(x) + 1.f + EPS_F);
    float q = (sqrtf(sqrt_arg) - 1.f) * (1.f / (2.f * EPS_F));
    return s * (q * q - 1.f);
}

__device__ __forceinline__ float rescale_f(float x) {
    return copysignf(sqrtf(fabsf(x) + 1.f) - 1.f, x) + EPS_F * x;
}

// R10 (resubmit — R7-slot bench was a GPU-acquisition timeout; kernel never
// ran): persistent + pipelined + barrier-free.
// Evidence ledger: R0/R6/R9 (one-shot waves, ideal traffic, incl. asm-forced
// 22-deep MLP) all pin at 2.0-2.1 TB/s; R8's prefetch was drained by the
// structural s_waitcnt vmcnt(0) before s_barrier; R7 (only kernel with
// cross-iteration request depth) hit 2.9 TB/s. The known 6.3 TB/s kernels on
// this chip are persistent grid-stride loops with independent, software-
// pipelined iterations and NO barriers. This kernel adopts that shape:
// - wave owns 64 consecutive t (60 outputs + 4 halo lanes), window taps come
//   from neighbor lanes via __shfl_down (no LDS -> no s_barrier -> nothing
//   ever drains vmcnt);
// - 2-deep software pipeline: issue task k+1's 10 loads, sched_barrier(0),
//   compute task k from the other register set;
// - 4096 persistent waves (1024x256), 9 tasks each.
__global__ __launch_bounds__(256) void nstep_qloss_kernel(
    const float* __restrict__ cur_q,    // (B,T,4)
    const float* __restrict__ next_q,   // (B,T,4)
    const float* __restrict__ log_p,    // (B,T)
    const float* __restrict__ reward,   // (B,T,4)
    const float* __restrict__ is_done,  // (B,T)
    const float* __restrict__ mask,     // (B,T)
    float* __restrict__ out,            // (B,T,4)
    int nrows)
{
    const int lane = threadIdx.x & 63;
    const int wid  = (blockIdx.x << 2) + (threadIdx.x >> 6);
    const int NW   = gridDim.x << 2;
    const int total = nrows * TASKS_PER_ROW;
    const int nj = (wid < total) ? ((total - 1 - wid) / NW + 1) : 0;
    if (nj == 0) return;

    const v4f* rew4 = (const v4f*)reward;
    const v4f* nq4  = (const v4f*)next_q;
    const v4f* cq4  = (const v4f*)cur_q;
    v4f*       out4 = (v4f*)out;

    const float g1 = GAMMA_F;
    const float g2 = g1 * g1;
    const float g3 = g2 * g1;
    const float g4 = g2 * g2;
    const float LSC = GAMMA_F * (1.f / 3.f);   // extra gamma * inv_num_q

    // two register sets for the 2-deep pipeline
    float mA, dA, pA, mB, dB, pB;
    v4f r0A, r1A, r2A, r3A, r4A, nqA, cqA;
    v4f r0B, r1B, r2B, r3B, r4B, nqB, cqB;

#define LOADK(S, TK) do {                                                   \
    int row_ = (TK) / TASKS_PER_ROW;                                        \
    int sub_ = (TK) - row_ * TASKS_PER_ROW;                                 \
    int tt_  = sub_ * WIDTH + lane;                                         \
    int b_   = row_ * T_DIM;                                                \
    int tl_  = (tt_     < T_DIM) ? tt_     : T_DIM - 1;                     \
    int h1_  = (tt_ + 1 < T_DIM) ? tt_ + 1 : T_DIM - 1;                     \
    int h2_  = (tt_ + 2 < T_DIM) ? tt_ + 2 : T_DIM - 1;                     \
    int h3_  = (tt_ + 3 < T_DIM) ? tt_ + 3 : T_DIM - 1;                     \
    int h4_  = (tt_ + 4 < T_DIM) ? tt_ + 4 : T_DIM - 1;                     \
    m##S  = mask[b_ + tl_];                                                 \
    d##S  = is_done[b_ + tl_];                                              \
    p##S  = log_p[b_ + tl_];                                                \
    r0##S = rew4[b_ + tl_];                                                 \
    r1##S = rew4[b_ + h1_];                                                 \
    r2##S = rew4[b_ + h2_];                                                 \
    r3##S = rew4[b_ + h3_];                                                 \
    r4##S = rew4[b_ + h4_];                                                 \
    nq##S = nq4 [b_ + h4_];                                                 \
    cq##S = cq4 [b_ + tl_];                                                 \
} while (0)

#define COMPUTEK(S, TK) do {                                                \
    int row_ = (TK) / TASKS_PER_ROW;                                        \
    int sub_ = (TK) - row_ * TASKS_PER_ROW;                                 \
    int tt_  = sub_ * WIDTH + lane;                                         \
    int b_   = row_ * T_DIM;                                                \
    int s4_  = (tt_ + 4 < T_DIM) ? tt_ + 4 : T_DIM - 1;                     \
    float v1_ = (tt_ + 1 < T_DIM) ? 1.f : 0.f;                              \
    float v2_ = (tt_ + 2 < T_DIM) ? 1.f : 0.f;                              \
    float v3_ = (tt_ + 3 < T_DIM) ? 1.f : 0.f;                              \
    float v4_ = (tt_ + 4 < T_DIM) ? 1.f : 0.f;                              \
    float MD_ = m##S * (1.f - d##S);                                        \
    float LZ_ = MD_ * p##S;                                                 \
    float M1_ = __shfl_down(m##S, 1);                                       \
    float M2_ = __shfl_down(m##S, 2);                                       \
    float M3_ = __shfl_down(m##S, 3);                                       \
    float M4_ = __shfl_down(m##S, 4);                                       \
    float L1_ = __shfl_down(LZ_, 1);                                        \
    float L2_ = __shfl_down(LZ_, 2);                                        \
    float L3_ = __shfl_down(LZ_, 3);                                        \
    float L4_ = __shfl_down(LZ_, 4);                                        \
    float MD4_ = __shfl_down(MD_, 4);                                       \
    float w0_ = m##S;                                                       \
    float w1_ = v1_ * g1 * M1_;                                             \
    float w2_ = v2_ * g2 * M2_;                                             \
    float w3_ = v3_ * g3 * M3_;                                             \
    float w4_ = v4_ * g4 * M4_;                                             \
    float a0_ = w0_ * r0##S.x, a1_ = w0_ * r0##S.y, a3_ = w0_ * r0##S.w;    \
    a0_ = fmaf(w1_, r1##S.x, a0_); a1_ = fmaf(w1_, r1##S.y, a1_); a3_ = fmaf(w1_, r1##S.w, a3_); \
    a0_ = fmaf(w2_, r2##S.x, a0_); a1_ = fmaf(w2_, r2##S.y, a1_); a3_ = fmaf(w2_, r2##S.w, a3_); \
    a0_ = fmaf(w3_, r3##S.x, a0_); a1_ = fmaf(w3_, r3##S.y, a1_); a3_ = fmaf(w3_, r3##S.w, a3_); \
    a0_ = fmaf(w4_, r4##S.x, a0_); a1_ = fmaf(w4_, r4##S.y, a1_); a3_ = fmaf(w4_, r4##S.w, a3_); \
    float Ls_ = LZ_;                                                        \
    Ls_ = fmaf(v1_ * g1, L1_, Ls_);                                         \
    Ls_ = fmaf(v2_ * g2, L2_, Ls_);                                         \
    Ls_ = fmaf(v3_ * g3, L3_, Ls_);                                         \
    Ls_ = fmaf(v4_ * g4, L4_, Ls_);                                         \
    Ls_ *= LSC;                                                             \
    float coeff_ = exp2f((float)s4_ * LOG2_GAMMA);                          \
    float gg_ = coeff_ * MD4_;                                              \
    float nt0_ = gg_ * inv_rescale_f(nq##S.x);                              \
    float nt1_ = gg_ * inv_rescale_f(nq##S.y);                              \
    float nt3_ = gg_ * inv_rescale_f(nq##S.w);                              \
    float tgt0_ = rescale_f(a0_ + nt0_ + 1.0f * Ls_);                       \
    float tgt1_ = rescale_f(a1_ + nt1_ + 2.0f * Ls_);                       \
    float tgt3_ = rescale_f(a3_ + nt3_ + 0.5f * Ls_);                       \
    float hm_ = 0.5f * m##S;                                                \
    float e0_ = cq##S.x - tgt0_;                                            \
    float e1_ = cq##S.y - tgt1_;                                            \
    float e3_ = cq##S.w - tgt3_;                                            \
    v4f o_;                                                                 \
    o_.x = hm_ * e0_ * e0_;                                                 \
    o_.y = hm_ * 0.5f * e1_ * e1_;                                          \
    o_.z = 0.f;                                                             \
    o_.w = hm_ * 2.0f * e3_ * e3_;                                          \
    if (lane < WIDTH && tt_ < T_DIM) out4[b_ + tt_] = o_;                   \
} while (0)

    int k = 0;
    LOADK(A, wid);
    for (;;) {
        int tk = wid + k * NW;
        if (k + 1 < nj) LOADK(B, tk + NW);
        __builtin_amdgcn_sched_barrier(0);
        COMPUTEK(A, tk);
        if (++k >= nj) break;
        tk = wid + k * NW;
        if (k + 1 < nj) LOADK(A, tk + NW);
        __builtin_amdgcn_sched_barrier(0);
        COMPUTEK(B, tk);
        if (++k >= nj) break;
    }
#undef LOADK
#undef COMPUTEK
}

extern "C" void kernel_launch(void* const* d_in, const int* in_sizes, int n_in,
                              void* d_out, int out_size, void* d_ws, size_t ws_size,
                              hipStream_t stream) {
    const float* cur_q   = (const float*)d_in[0];
    const float* next_q  = (const float*)d_in[1];
    const float* log_p   = (const float*)d_in[2];
    const float* reward  = (const float*)d_in[3];
    const float* is_done = (const float*)d_in[4];
    const float* mask    = (const float*)d_in[5];
    float* out = (float*)d_out;

    int BT = in_sizes[2];               // B*T (element count)
    int nrows = BT / T_DIM;             // 4096 rows
    hipLaunchKernelGGL(nstep_qloss_kernel, dim3(NBLOCKS), dim3(TPB), 0, stream,
                       cur_q, next_q, log_p, reward, is_done, mask, out, nrows);
}